// Round 4
// baseline (53.941 us; speedup 1.0000x reference)
//
#include <hip/hip_runtime.h>
#include <hip/hip_bf16.h>

typedef __attribute__((ext_vector_type(8))) short s16x8;
typedef __attribute__((ext_vector_type(8))) unsigned short u16x8;
typedef __attribute__((ext_vector_type(4))) float f32x4;
typedef __attribute__((ext_vector_type(4))) unsigned short u16x4;
typedef __attribute__((ext_vector_type(4))) float fl4;

__device__ __forceinline__ unsigned short f2bf(float f) {
  union { __hip_bfloat16 b; unsigned short u; } cv;
  cv.b = __float2bfloat16(f);
  return cv.u;
}

// HSTU fused, B=8 H=4 D=V=64 SEQ=1024. No workspace (d_ws poison-fill costs ~42us).
// Grid: 32 bh x 32 row-groups (32 q-rows) = 1024 blocks (4/CU), 4 waves.
// Waves {0,1}: rows {lo,hi} x KV-half 0; waves {2,3}: same rows x KV-half 1.
// No softmax -> halves combine by addition (LDS reduction at end).
__global__ __launch_bounds__(256, 4)
void hstu_fused(const float* __restrict__ tq, const float* __restrict__ tk,
                const float* __restrict__ tv, const int* __restrict__ ncand,
                float* __restrict__ out)
{
  const int bid = (int)blockIdx.x;
  const int bh  = bid & 31;             // same bh -> same XCD (stride 32)
  const int qg  = 31 - (bid >> 5);      // heavy-first dispatch
  const int b = bh >> 2, h = bh & 3;
  const int tid = (int)threadIdx.x;
  const int w   = tid >> 6;
  const int sub = w & 1;                // row sub-group (16 rows)
  const int hf  = w >> 1;               // kv half
  const int l   = tid & 63;
  const int rl  = l & 15, g = l >> 4;
  const int T   = 1024 - ncand[b];
  const int qr  = qg*32 + sub*16;
  const int rq  = qr + rl;

  // LDS: K0[4096] V0[4096] K1[4096] V1[4096] shorts (32 KB).
  __shared__ unsigned short S[16384];
  unsigned short* KH = S + hf*8192;
  unsigned short* VH = KH + 4096;

  const int pt = sub*64 + l;            // pair-local tid 0..127 (pair = waves {2hf,2hf+1})
  const int sy = pt >> 1, sq = pt & 1;  // K staging: row, half-row
  const int vc = pt & 63, vq = pt >> 6; // V staging: col, g-group

  // ---- Q frags in-reg (alpha=1/8 folded): lane(rl,g) holds d in {8g..8g+7}u{32+8g..}
  s16x8 qf0, qf1;
  {
    const float* qs = tq + ((size_t)(b*1024 + rq))*256 + h*64;
    fl4 a  = *(const fl4*)(qs + g*8);
    fl4 b2 = *(const fl4*)(qs + g*8 + 4);
    fl4 c  = *(const fl4*)(qs + 32 + g*8);
    fl4 d2 = *(const fl4*)(qs + 36 + g*8);
#pragma unroll
    for (int j = 0; j < 4; ++j) {
      qf0[j]   = (short)f2bf(a[j]  * 0.125f);
      qf0[j+4] = (short)f2bf(b2[j] * 0.125f);
      qf1[j]   = (short)f2bf(c[j]  * 0.125f);
      qf1[j+4] = (short)f2bf(d2[j] * 0.125f);
    }
  }

  f32x4 zero = {0.f, 0.f, 0.f, 0.f};
  f32x4 oacc[4];
#pragma unroll
  for (int i = 0; i < 4; ++i) oacc[i] = zero;

  const int nkv = (qg == 0) ? 16 : (qg >> 1) + 1;  // qg0 holds contextual rows
  const int nh  = (nkv + 1) >> 1;                  // uniform trip count for all waves

  for (int it = 0; it < nh; ++it) {
    const int t = hf*nh + it;
    const bool act = (t < nkv);
    if (act) {
      // ---- stage K tile (pair coop): rows sy, 32 floats at col sq*32; XOR-swizzled
      const float* ks = tk + ((size_t)(b*1024 + t*64 + sy))*256 + h*64 + sq*32;
      char* krow = (char*)KH + sy*128;
      const int ssw = (sy & 7) << 4;
#pragma unroll
      for (int j2 = 0; j2 < 4; ++j2) {
        fl4 v0 = *(const fl4*)(ks + j2*8);
        fl4 v1 = *(const fl4*)(ks + j2*8 + 4);
        u16x8 p;
#pragma unroll
        for (int j = 0; j < 4; ++j) { p[j] = f2bf(v0[j]); p[j+4] = f2bf(v1[j]); }
        *(u16x8*)(krow + (((sq*4 + j2)*16) ^ ssw)) = p;
      }
      // ---- stage V tile PV-permuted (1/2048 folded):
      // short idx ((kp*4+gg)*64+c)*8 + 4*tu + j  =  V[32kp+16tu+4gg+j][c]
      const float* vs = tv + ((size_t)(b*1024 + t*64))*256 + h*64 + vc;
#pragma unroll
      for (int kp = 0; kp < 2; ++kp)
#pragma unroll
        for (int tu = 0; tu < 2; ++tu)
#pragma unroll
          for (int gq = 0; gq < 2; ++gq) {
            const int gg = vq*2 + gq;
            const int y0 = kp*32 + tu*16 + gg*4;
            u16x4 p;
#pragma unroll
            for (int j = 0; j < 4; ++j)
              p[j] = f2bf(vs[(size_t)(y0 + j)*256] * 4.8828125e-4f);
            *(u16x4*)&VH[((kp*4 + gg)*64 + vc)*8 + tu*4] = p;
          }
    }
    __syncthreads();

    if (act) {
      // ---- QK^T swapped: S^T[y][q], A=K frag (rows y), B=Q frag
      f32x4 sacc[4];
#pragma unroll
      for (int i = 0; i < 4; ++i) sacc[i] = zero;
      __builtin_amdgcn_s_setprio(1);
#pragma unroll
      for (int t4 = 0; t4 < 4; ++t4) {
        const int kr = t4*16 + rl;
        const char* base = (const char*)KH + kr*128;
        const int sw = (kr & 7) << 4;
        s16x8 kf0 = *(const s16x8*)(base + ((g*16) ^ sw));
        s16x8 kf1 = *(const s16x8*)(base + ((64 + g*16) ^ sw));
        sacc[t4] = __builtin_amdgcn_mfma_f32_16x16x32_bf16(kf0, qf0, sacc[t4], 0, 0, 0);
        sacc[t4] = __builtin_amdgcn_mfma_f32_16x16x32_bf16(kf1, qf1, sacc[t4], 0, 0, 0);
      }
      __builtin_amdgcn_s_setprio(0);
      // ---- silu + mask + pack P into PV A-frags
      s16x8 pa0, pa1;
#pragma unroll
      for (int t4 = 0; t4 < 4; ++t4) {
#pragma unroll
        for (int r = 0; r < 4; ++r) {
          const int y = t*64 + t4*16 + 4*g + r;
          const float s = sacc[t4][r];
          const float sig = __builtin_amdgcn_rcpf(1.f + __expf(-s));
          const bool valid = (rq < 8) ? (y < T)
                           : ((y <= rq) && ((rq < T) || (y < T) || (y == rq)));
          const float a = valid ? s * sig : 0.f;
          const short bv = (short)f2bf(a);
          if (t4 < 2) pa0[(t4 & 1)*4 + r] = bv;
          else        pa1[(t4 & 1)*4 + r] = bv;
        }
      }
      // ---- PV from permuted V (B-frags are single 16B LDS reads)
      __builtin_amdgcn_s_setprio(1);
#pragma unroll
      for (int vt = 0; vt < 4; ++vt) {
        const s16x8 vf0 = *(const s16x8*)&VH[((0*4 + g)*64 + vt*16 + rl)*8];
        oacc[vt] = __builtin_amdgcn_mfma_f32_16x16x32_bf16(pa0, vf0, oacc[vt], 0, 0, 0);
        const s16x8 vf1 = *(const s16x8*)&VH[((1*4 + g)*64 + vt*16 + rl)*8];
        oacc[vt] = __builtin_amdgcn_mfma_f32_16x16x32_bf16(pa1, vf1, oacc[vt], 0, 0, 0);
      }
      __builtin_amdgcn_s_setprio(0);
    }
    __syncthreads();   // protect LDS overwrite next iter
  }

  // ---- cross-half reduction: waves hf=1 dump partials, hf=0 adds + stores
  float* Ored = (float*)S;   // 8 KB needed; overlaps K0/V0 (safe after final barrier)
  if (hf == 1) {
#pragma unroll
    for (int vt = 0; vt < 4; ++vt)
#pragma unroll
      for (int r = 0; r < 4; ++r)
        Ored[sub*1024 + (4*g + r)*64 + vt*16 + rl] = oacc[vt][r];
  }
  __syncthreads();
  if (hf == 0) {
    float* dst = out + ((size_t)(b*1024 + qr))*256 + h*64;
#pragma unroll
    for (int vt = 0; vt < 4; ++vt)
#pragma unroll
      for (int r = 0; r < 4; ++r)
        dst[(size_t)(4*g + r)*256 + vt*16 + rl] =
            oacc[vt][r] + Ored[sub*1024 + (4*g + r)*64 + vt*16 + rl];
  }
}

extern "C" void kernel_launch(void* const* d_in, const int* in_sizes, int n_in,
                              void* d_out, int out_size, void* d_ws, size_t ws_size,
                              hipStream_t stream) {
  (void)in_sizes; (void)n_in; (void)out_size; (void)d_ws; (void)ws_size;
  const float* tq = (const float*)d_in[0];
  const float* tk = (const float*)d_in[1];
  const float* tv = (const float*)d_in[2];
  const int*   nc = (const int*)d_in[4];
  float* out = (float*)d_out;
  hipLaunchKernelGGL(hstu_fused, dim3(1024), dim3(256), 0, stream, tq, tk, tv, nc, out);
}

// Round 6
// 42.636 us; speedup vs baseline: 1.2652x; 1.2652x over previous
//
#include <hip/hip_runtime.h>
#include <hip/hip_bf16.h>

typedef __attribute__((ext_vector_type(8))) short s16x8;
typedef __attribute__((ext_vector_type(4))) float f32x4;
typedef __attribute__((ext_vector_type(4))) unsigned short u16x4;
typedef __attribute__((ext_vector_type(4))) float fl4;

__device__ __forceinline__ unsigned short f2bf(float f) {
  union { __hip_bfloat16 b; unsigned short u; } cv;
  cv.b = __float2bfloat16(f);
  return cv.u;
}

// HSTU fused, B=8 H=4 D=V=64 SEQ=1024. R1 structure; ONLY change: V image is
// built from coalesced row-major fl4 reads + in-register permute + packed b32
// LDS writes (kills the 4B-at-1KB-stride global gather = 16x L2 amplification).
// V image (same as R1): short[((kp*4+gg)*64+col)*8 + tu*4 + j] = V[32kp+16tu+4gg+j][col]/2048.
__global__ __launch_bounds__(256)
void hstu_fused(const float* __restrict__ tq, const float* __restrict__ tk,
                const float* __restrict__ tv, const int* __restrict__ ncand,
                float* __restrict__ out)
{
  const int bid = (int)blockIdx.x;
  const int bh  = bid & 31;            // same (b,h) -> same XCD (stride 32)
  const int jp  = bid >> 5;
  const int qtile = (jp & 1) ? (15 - (jp >> 1)) : (jp >> 1);  // heavy+light pairing
  const int b = bh >> 2, h = bh & 3;
  const int tid = (int)threadIdx.x;
  const int w = tid >> 6, l = tid & 63;
  const int rl = l & 15, g = l >> 4;
  const int T = 1024 - ncand[b];
  const int qbase = qtile << 6;

  __shared__ unsigned short Klds[4096];  // [64][64] bf16, XOR-swizzled rows
  __shared__ unsigned short Vp[4096];    // PV-permuted image (see above)

  const int sy = tid >> 2, sq4 = tid & 3;   // K staging: 4 threads/row
  const int ssw = (sy & 7) << 4;
  const int vch = tid & 15;                 // V staging: col chunk (4 floats)

  // ---- Q frags in-reg (alpha=1/8 folded): lane(rl,g) d in {8g..8g+7} u {32+8g..}
  const int rq = qbase + w*16 + rl;
  s16x8 qf0, qf1;
  {
    const float* qs = tq + ((size_t)(b*1024 + rq))*256 + h*64;
    fl4 a  = *(const fl4*)(qs + g*8);
    fl4 b2 = *(const fl4*)(qs + g*8 + 4);
    fl4 c  = *(const fl4*)(qs + 32 + g*8);
    fl4 d2 = *(const fl4*)(qs + 36 + g*8);
#pragma unroll
    for (int j = 0; j < 4; ++j) {
      qf0[j]   = (short)f2bf(a[j]  * 0.125f);
      qf0[j+4] = (short)f2bf(b2[j] * 0.125f);
      qf1[j]   = (short)f2bf(c[j]  * 0.125f);
      qf1[j+4] = (short)f2bf(d2[j] * 0.125f);
    }
  }

  f32x4 zero = {0.f, 0.f, 0.f, 0.f};
  f32x4 oacc[4];
#pragma unroll
  for (int i = 0; i < 4; ++i) oacc[i] = zero;

  const int nkv = (qtile == 0) ? 16 : (qtile + 1);

  for (int t = 0; t < nkv; ++t) {
    // ---- stage K tile: coalesced fl4, swizzled row-major writes (as R1) ----
    {
      const float* ks = tk + ((size_t)(b*1024 + t*64 + sy))*256 + h*64;
      char* krow = (char*)Klds + sy*128;
#pragma unroll
      for (int j2 = 0; j2 < 4; ++j2) {
        fl4 v = *(const fl4*)(ks + (sq4 + 4*j2)*4);
        u16x4 p;
        p[0] = f2bf(v[0]); p[1] = f2bf(v[1]);
        p[2] = f2bf(v[2]); p[3] = f2bf(v[3]);
        *(u16x4*)(krow + (((sq4 + 4*j2)*8) ^ ssw)) = p;
      }
    }
    // ---- stage V tile: coalesced row-pair fl4 reads -> packed b32 permuted writes
    {
      unsigned int* vp32 = (unsigned int*)Vp;
#pragma unroll
      for (int c = 0; c < 2; ++c) {
        const int y = (16*c + (tid >> 4)) * 2;          // even row of the pair
        const float* vs = tv + ((size_t)(b*1024 + t*64 + y))*256 + h*64 + vch*4;
        fl4 v0 = *(const fl4*)vs;                        // row y
        fl4 v1 = *(const fl4*)(vs + 256);                // row y+1
        const int kp = y >> 5, tu = (y >> 4) & 1, gg = (y >> 2) & 3, j0 = y & 3;
        const int dbase = ((kp*4 + gg)*64 + vch*4)*4 + tu*2 + (j0 >> 1);  // uint idx
#pragma unroll
        for (int ji = 0; ji < 4; ++ji) {
          const unsigned int lo = f2bf(v0[ji] * 4.8828125e-4f);
          const unsigned int hi = f2bf(v1[ji] * 4.8828125e-4f);
          vp32[dbase + ji*4] = lo | (hi << 16);
        }
      }
    }
    __syncthreads();

    if (qtile != 0 || t == 0 || w == 0) {
      // ---- QK^T swapped: A=K frag (rows y), B=Q frag (cols r)
      f32x4 sacc[4];
#pragma unroll
      for (int i = 0; i < 4; ++i) sacc[i] = zero;
#pragma unroll
      for (int t4 = 0; t4 < 4; ++t4) {
        const int kr = t4*16 + rl;
        const char* base = (const char*)Klds + kr*128;
        const int sw = (kr & 7) << 4;
        s16x8 kf0 = *(const s16x8*)(base + ((g*16) ^ sw));
        s16x8 kf1 = *(const s16x8*)(base + ((64 + g*16) ^ sw));
        sacc[t4] = __builtin_amdgcn_mfma_f32_16x16x32_bf16(kf0, qf0, sacc[t4], 0, 0, 0);
        sacc[t4] = __builtin_amdgcn_mfma_f32_16x16x32_bf16(kf1, qf1, sacc[t4], 0, 0, 0);
      }
      // ---- silu + mask + pack P (slot (g,i): y = 16(i>>2)+4g+(i&3) (+32 pa1))
      s16x8 pa0, pa1;
#pragma unroll
      for (int t4 = 0; t4 < 4; ++t4) {
#pragma unroll
        for (int r = 0; r < 4; ++r) {
          const int y = t*64 + t4*16 + 4*g + r;
          const float s = sacc[t4][r];
          const float sig = __builtin_amdgcn_rcpf(1.f + __expf(-s));
          const bool valid = (rq < 8) ? (y < T)
                           : ((y <= rq) && ((rq < T) || (y < T) || (y == rq)));
          const float a = valid ? s * sig : 0.f;
          const short bv = (short)f2bf(a);
          if (t4 < 2) pa0[(t4 & 1)*4 + r] = bv;
          else        pa1[(t4 & 1)*4 + r] = bv;
        }
      }
      // ---- PV from permuted V image (single 16B LDS reads, as R1)
#pragma unroll
      for (int vt = 0; vt < 4; ++vt) {
        const s16x8 vf0 = *(const s16x8*)&Vp[((0*4 + g)*64 + vt*16 + rl)*8];
        oacc[vt] = __builtin_amdgcn_mfma_f32_16x16x32_bf16(pa0, vf0, oacc[vt], 0, 0, 0);
        const s16x8 vf1 = *(const s16x8*)&Vp[((1*4 + g)*64 + vt*16 + rl)*8];
        oacc[vt] = __builtin_amdgcn_mfma_f32_16x16x32_bf16(pa1, vf1, oacc[vt], 0, 0, 0);
      }
    }
    __syncthreads();   // protect LDS overwrite next iter
  }

  // ---- epilogue: O rows 4g+r, cols vt*16+rl (same as R1)
  float* dst = out + ((size_t)(b*1024 + qbase + w*16))*256 + h*64;
#pragma unroll
  for (int vt = 0; vt < 4; ++vt)
#pragma unroll
    for (int r = 0; r < 4; ++r)
      dst[(size_t)(4*g + r)*256 + vt*16 + rl] = oacc[vt][r];
}

extern "C" void kernel_launch(void* const* d_in, const int* in_sizes, int n_in,
                              void* d_out, int out_size, void* d_ws, size_t ws_size,
                              hipStream_t stream) {
  (void)in_sizes; (void)n_in; (void)out_size; (void)d_ws; (void)ws_size;
  const float* tq = (const float*)d_in[0];
  const float* tk = (const float*)d_in[1];
  const float* tv = (const float*)d_in[2];
  const int*   nc = (const int*)d_in[4];
  float* out = (float*)d_out;
  hipLaunchKernelGGL(hstu_fused, dim3(512), dim3(256), 0, stream, tq, tk, tv, nc, out);
}

// Round 7
// 42.178 us; speedup vs baseline: 1.2789x; 1.0109x over previous
//
#include <hip/hip_runtime.h>
#include <hip/hip_bf16.h>

typedef __attribute__((ext_vector_type(8))) short s16x8;
typedef __attribute__((ext_vector_type(4))) float f32x4;
typedef __attribute__((ext_vector_type(4))) unsigned short u16x4;
typedef __attribute__((ext_vector_type(4))) float fl4;

__device__ __forceinline__ unsigned short f2bf(float f) {
  union { __hip_bfloat16 b; unsigned short u; } cv;
  cv.b = __float2bfloat16(f);
  return cv.u;
}

// HSTU fused, B=8 H=4 D=V=64 SEQ=1024. R6 base + (1) balanced co-resident
// pairing (every CU's 2 blocks sum to 18-19 KV-iters, was 8..28) and
// (2) true LDS double-buffer: stage(t+1) issues before compute(t), ONE
// barrier/iter -> global-load latency hides under MFMA+silu.
// V image: short[((kp*4+gg)*64+col)*8 + tu*4 + j] = V[32kp+16tu+4gg+j][col]/2048.
__global__ __launch_bounds__(256)
void hstu_fused(const float* __restrict__ tq, const float* __restrict__ tk,
                const float* __restrict__ tv, const int* __restrict__ ncand,
                float* __restrict__ out)
{
  const int bid = (int)blockIdx.x;
  const int bh  = bid & 31;            // same (b,h) -> same XCD (stride 32)
  const int jp  = bid >> 5;
  // balanced pairs (jp, jp+8) co-reside on one CU; nkv sums 18-19:
  // jp: 0..7 -> {0,15,14,13,12,11,10,9}; 8..15 -> {2,1,3,4,5,6,7,8}
  const int qtile = (jp < 8) ? (jp == 0 ? 0 : 16 - jp)
                             : (jp == 8 ? 2 : (jp == 9 ? 1 : jp - 7));
  const int b = bh >> 2, h = bh & 3;
  const int tid = (int)threadIdx.x;
  const int w = tid >> 6, l = tid & 63;
  const int rl = l & 15, g = l >> 4;
  const int T = 1024 - ncand[b];
  const int qbase = qtile << 6;

  __shared__ unsigned short Klds[2][4096];  // [64][64] bf16, XOR-swizzled rows
  __shared__ unsigned short Vp[2][4096];    // PV-permuted image

  const int sy = tid >> 2, sq4 = tid & 3;   // K staging: 4 threads/row
  const int ssw = (sy & 7) << 4;
  const int vch = tid & 15;                 // V staging: col chunk (4 floats)

  // ---- Q frags in-reg (alpha=1/8 folded): lane(rl,g) d in {8g..8g+7} u {32+8g..}
  const int rq = qbase + w*16 + rl;
  s16x8 qf0, qf1;
  {
    const float* qs = tq + ((size_t)(b*1024 + rq))*256 + h*64;
    fl4 a  = *(const fl4*)(qs + g*8);
    fl4 b2 = *(const fl4*)(qs + g*8 + 4);
    fl4 c  = *(const fl4*)(qs + 32 + g*8);
    fl4 d2 = *(const fl4*)(qs + 36 + g*8);
#pragma unroll
    for (int j = 0; j < 4; ++j) {
      qf0[j]   = (short)f2bf(a[j]  * 0.125f);
      qf0[j+4] = (short)f2bf(b2[j] * 0.125f);
      qf1[j]   = (short)f2bf(c[j]  * 0.125f);
      qf1[j+4] = (short)f2bf(d2[j] * 0.125f);
    }
  }

  auto stage = [&](int buf, int t) {
    // K tile: coalesced fl4, swizzled row-major writes
    const float* ks = tk + ((size_t)(b*1024 + t*64 + sy))*256 + h*64;
    char* krow = (char*)Klds[buf] + sy*128;
#pragma unroll
    for (int j2 = 0; j2 < 4; ++j2) {
      fl4 v = *(const fl4*)(ks + (sq4 + 4*j2)*4);
      u16x4 p;
      p[0] = f2bf(v[0]); p[1] = f2bf(v[1]);
      p[2] = f2bf(v[2]); p[3] = f2bf(v[3]);
      *(u16x4*)(krow + (((sq4 + 4*j2)*8) ^ ssw)) = p;
    }
    // V tile: coalesced row-pair fl4 reads -> packed b32 permuted writes
    unsigned int* vp32 = (unsigned int*)Vp[buf];
#pragma unroll
    for (int c = 0; c < 2; ++c) {
      const int y = (16*c + (tid >> 4)) * 2;          // even row of the pair
      const float* vs = tv + ((size_t)(b*1024 + t*64 + y))*256 + h*64 + vch*4;
      fl4 v0 = *(const fl4*)vs;                        // row y
      fl4 v1 = *(const fl4*)(vs + 256);                // row y+1
      const int kp = y >> 5, tu = (y >> 4) & 1, gg = (y >> 2) & 3, j0 = y & 3;
      const int dbase = ((kp*4 + gg)*64 + vch*4)*4 + tu*2 + (j0 >> 1);  // uint idx
#pragma unroll
      for (int ji = 0; ji < 4; ++ji) {
        const unsigned int lo = f2bf(v0[ji] * 4.8828125e-4f);
        const unsigned int hi = f2bf(v1[ji] * 4.8828125e-4f);
        vp32[dbase + ji*4] = lo | (hi << 16);
      }
    }
  };

  f32x4 zero = {0.f, 0.f, 0.f, 0.f};
  f32x4 oacc[4];
#pragma unroll
  for (int i = 0; i < 4; ++i) oacc[i] = zero;

  const int nkv = (qtile == 0) ? 16 : (qtile + 1);

  stage(0, 0);
  __syncthreads();

  for (int t = 0; t < nkv; ++t) {
    const int cur = t & 1;
    if (t + 1 < nkv) stage(cur ^ 1, t + 1);   // loads issue early; latency hides

    if (qtile != 0 || t == 0 || w == 0) {
      // ---- QK^T swapped: A=K frag (rows y), B=Q frag (cols r)
      f32x4 sacc[4];
#pragma unroll
      for (int i = 0; i < 4; ++i) sacc[i] = zero;
      const char* kb = (const char*)Klds[cur];
#pragma unroll
      for (int t4 = 0; t4 < 4; ++t4) {
        const int kr = t4*16 + rl;
        const char* base = kb + kr*128;
        const int sw = (kr & 7) << 4;
        s16x8 kf0 = *(const s16x8*)(base + ((g*16) ^ sw));
        s16x8 kf1 = *(const s16x8*)(base + ((64 + g*16) ^ sw));
        sacc[t4] = __builtin_amdgcn_mfma_f32_16x16x32_bf16(kf0, qf0, sacc[t4], 0, 0, 0);
        sacc[t4] = __builtin_amdgcn_mfma_f32_16x16x32_bf16(kf1, qf1, sacc[t4], 0, 0, 0);
      }
      // ---- silu + mask + pack P (slot (g,i): y = 16(i>>2)+4g+(i&3) (+32 pa1))
      s16x8 pa0, pa1;
#pragma unroll
      for (int t4 = 0; t4 < 4; ++t4) {
#pragma unroll
        for (int r = 0; r < 4; ++r) {
          const int y = t*64 + t4*16 + 4*g + r;
          const float s = sacc[t4][r];
          const float sig = __builtin_amdgcn_rcpf(1.f + __expf(-s));
          const bool valid = (rq < 8) ? (y < T)
                           : ((y <= rq) && ((rq < T) || (y < T) || (y == rq)));
          const float a = valid ? s * sig : 0.f;
          const short bv = (short)f2bf(a);
          if (t4 < 2) pa0[(t4 & 1)*4 + r] = bv;
          else        pa1[(t4 & 1)*4 + r] = bv;
        }
      }
      // ---- PV from permuted V image (single 16B LDS reads)
      const unsigned short* vb = Vp[cur];
#pragma unroll
      for (int vt = 0; vt < 4; ++vt) {
        const s16x8 vf0 = *(const s16x8*)&vb[((0*4 + g)*64 + vt*16 + rl)*8];
        oacc[vt] = __builtin_amdgcn_mfma_f32_16x16x32_bf16(pa0, vf0, oacc[vt], 0, 0, 0);
        const s16x8 vf1 = *(const s16x8*)&vb[((1*4 + g)*64 + vt*16 + rl)*8];
        oacc[vt] = __builtin_amdgcn_mfma_f32_16x16x32_bf16(pa1, vf1, oacc[vt], 0, 0, 0);
      }
    }
    __syncthreads();   // publishes buf^1 for next iter; protects overwrite
  }

  // ---- epilogue: O rows 4g+r, cols vt*16+rl
  float* dst = out + ((size_t)(b*1024 + qbase + w*16))*256 + h*64;
#pragma unroll
  for (int vt = 0; vt < 4; ++vt)
#pragma unroll
    for (int r = 0; r < 4; ++r)
      dst[(size_t)(4*g + r)*256 + vt*16 + rl] = oacc[vt][r];
}

extern "C" void kernel_launch(void* const* d_in, const int* in_sizes, int n_in,
                              void* d_out, int out_size, void* d_ws, size_t ws_size,
                              hipStream_t stream) {
  (void)in_sizes; (void)n_in; (void)out_size; (void)d_ws; (void)ws_size;
  const float* tq = (const float*)d_in[0];
  const float* tk = (const float*)d_in[1];
  const float* tv = (const float*)d_in[2];
  const int*   nc = (const int*)d_in[4];
  float* out = (float*)d_out;
  hipLaunchKernelGGL(hstu_fused, dim3(512), dim3(256), 0, stream, tq, tk, tv, nc, out);
}